// Round 10
// baseline (188.089 us; speedup 1.0000x reference)
//
#include <hip/hip_runtime.h>

// Problem dims (fixed by reference)
#define Bq 32
#define Sq 64
#define Iq 256
#define Hq 256
#define Oq 128
#define Fq 512          // Iq + Hq
#define WPB 16          // workgroups per batch (R14: was 8)
#define NT 256          // threads per workgroup (R14: was 512)
#define PRE_S 62        // x steps preloaded in LDS: 62KB + 1KB hbuf + flag

// R14: two-batch co-residency for stall hiding. Transport-latency branch is
// CLOSED: R2(barrier)=102, R6(flag)=101, R12(sc0 read)=112, R13(dual
// publish)=125 -- four transports all >=99us, every LLC-dodge failed.
// Counters say step = ~1875cy VALU-pipe + ~1875cy stall (VALUBusy~50%).
// The stall is exposed because each CU hosts ONE WG of ONE batch; when it
// waits on its h-chain the CU idles. Reshape: 16 WGs/batch x 256 threads,
// grid 512 on 256 CUs -> 2 WGs/CU, with b = blk>>4 so co-resident WGs
// (blocks c, c+256) belong to DIFFERENT batches with independent serial
// chains -> WG-B's VALU fills WG-A's stall. Per-thread work, lane mapping
// (16 lanes/row, 32 elems/thread), and arithmetic order are bit-identical
// to R7; the drift<2 slot invariant is WPB-independent. Pollers/batch
// double (2x proven budget; R5's failure was 8x -- monitored via FETCH).
// Transport is EXACTLY R7's proven path (agent atomics + LDS flag).
__global__ __launch_bounds__(NT, 2) void stpn_main(
    const float* __restrict__ x,     // (B,S,I)
    const float* __restrict__ w,     // (H,F)
    const float* __restrict__ wl,    // (H,F)
    const float* __restrict__ wgm,   // (H,F)
    const float* __restrict__ bias,  // (H)
    const float* __restrict__ ow,    // (O,H)
    const float* __restrict__ ob,    // (O)
    float* __restrict__ out,         // [tag(B*O) | h_fin(B*H) | f_fin(B*H*F)]
    unsigned long long* __restrict__ hb) // [2][B][H] (tag<<32|bits) slots
{
    const int blk   = blockIdx.x;
    const int b     = blk >> 4;       // batch: blocks c and c+256 differ by 16
    const int chunk = blk & 15;       // 0..15
    const int h0    = chunk * 16;
    const int tid   = threadIdx.x;
    const int lr    = tid & 15;       // lane within row
    const int r     = tid >> 4;       // row 0..15
    const int row   = h0 + r;
    const int ln    = tid & 63;       // lane within wave
    const int wv    = tid >> 6;       // wave id within wg (0..3)

    __shared__ float xall[PRE_S * Iq];   // 62 KB
    __shared__ float hbuf[Hq];           // 1 KB: h_{t-1} broadcast buffer
    __shared__ unsigned hflag;           // step tag of hbuf contents

    // Static params + fast-weight state in registers for all 64 steps.
    float fw[32], fl[32], fg[32], ff[32];
    const size_t rowoff = (size_t)row * Fq;
#pragma unroll
    for (int j = 0; j < 8; ++j) {
        const int c = 4 * lr + 64 * j;
        *(float4*)&fw[4*j] = *(const float4*)(w   + rowoff + c);
        *(float4*)&fl[4*j] = *(const float4*)(wl  + rowoff + c);
        *(float4*)&fg[4*j] = *(const float4*)(wgm + rowoff + c);
    }
#pragma unroll
    for (int j = 0; j < 32; ++j) ff[j] = 0.f;

    // Prologue x preload: 62*256/4 = 3968 float4 = 256*15 + 128.
    {
        const float4* xs = (const float4*)(x + (size_t)b * Sq * Iq);
        float4* xd = (float4*)xall;
#pragma unroll
        for (int k = 0; k < 15; ++k)
            xd[tid + NT * k] = xs[tid + NT * k];
        if (tid < 128) xd[tid + 3840] = xs[tid + 3840];
    }
    if (tid < Hq) hbuf[tid] = 0.f;    // t=0 reads h = 0
    if (tid == 0) hflag = 0u;
    const float brow = bias[row];
    const float* xb = x + (size_t)b * Sq * Iq;
    __syncthreads();                  // covers preload + hbuf/hflag init

    for (int t = 0; t < Sq; ++t) {
        // ---- x-part of fused pre+nsq (js 0..3): no transport dependency ----
        float pre = 0.f, nsq = 0.f;
        if (t < PRE_S) {
            const float* xpart = xall + t * Iq;
#pragma unroll
            for (int j = 0; j < 4; ++j) {
                const float4 tv = *(const float4*)&xpart[4 * lr + 64 * j];
                float tw;
                tw = fw[4*j+0] + ff[4*j+0]; pre = fmaf(tv.x, tw, pre); nsq = fmaf(tw, tw, nsq);
                tw = fw[4*j+1] + ff[4*j+1]; pre = fmaf(tv.y, tw, pre); nsq = fmaf(tw, tw, nsq);
                tw = fw[4*j+2] + ff[4*j+2]; pre = fmaf(tv.z, tw, pre); nsq = fmaf(tw, tw, nsq);
                tw = fw[4*j+3] + ff[4*j+3]; pre = fmaf(tv.w, tw, pre); nsq = fmaf(tw, tw, nsq);
            }
        } else {
            const float* xpart = xb + (size_t)t * Iq;
#pragma unroll
            for (int j = 0; j < 4; ++j) {
                const float4 tv = *(const float4*)&xpart[4 * lr + 64 * j];
                float tw;
                tw = fw[4*j+0] + ff[4*j+0]; pre = fmaf(tv.x, tw, pre); nsq = fmaf(tw, tw, nsq);
                tw = fw[4*j+1] + ff[4*j+1]; pre = fmaf(tv.y, tw, pre); nsq = fmaf(tw, tw, nsq);
                tw = fw[4*j+2] + ff[4*j+2]; pre = fmaf(tv.z, tw, pre); nsq = fmaf(tw, tw, nsq);
                tw = fw[4*j+3] + ff[4*j+3]; pre = fmaf(tv.w, tw, pre); nsq = fmaf(tw, tw, nsq);
            }
        }

        // ---- transport: wave0 fetches h_{t-1}, siblings wait on LDS flag ----
        if (t > 0) {
            const unsigned tt = (unsigned)t;
            if (wv == 0) {
                unsigned long long* s0 =
                    hb + (size_t)((t - 1) & 1) * Bq * Hq + (size_t)b * Hq + ln;
                unsigned long long v0, v1, v2, v3;
                do {
                    v0 = __hip_atomic_load(s0,       __ATOMIC_RELAXED, __HIP_MEMORY_SCOPE_AGENT);
                    v1 = __hip_atomic_load(s0 + 64,  __ATOMIC_RELAXED, __HIP_MEMORY_SCOPE_AGENT);
                    v2 = __hip_atomic_load(s0 + 128, __ATOMIC_RELAXED, __HIP_MEMORY_SCOPE_AGENT);
                    v3 = __hip_atomic_load(s0 + 192, __ATOMIC_RELAXED, __HIP_MEMORY_SCOPE_AGENT);
                } while (!((unsigned)(v0 >> 32) == tt && (unsigned)(v1 >> 32) == tt &&
                           (unsigned)(v2 >> 32) == tt && (unsigned)(v3 >> 32) == tt));
                hbuf[ln      ] = __uint_as_float((unsigned)(v0 & 0xffffffffu));
                hbuf[ln + 64 ] = __uint_as_float((unsigned)(v1 & 0xffffffffu));
                hbuf[ln + 128] = __uint_as_float((unsigned)(v2 & 0xffffffffu));
                hbuf[ln + 192] = __uint_as_float((unsigned)(v3 & 0xffffffffu));
                if (ln == 0)
                    __hip_atomic_store(&hflag, tt, __ATOMIC_RELEASE,
                                       __HIP_MEMORY_SCOPE_WORKGROUP);
            } else {
                while (__hip_atomic_load(&hflag, __ATOMIC_ACQUIRE,
                                         __HIP_MEMORY_SCOPE_WORKGROUP) != tt) {}
            }
        }

        // ---- h-part (js 4..7); keep operands in regs for the shadow ----
        float4 hr[4];
#pragma unroll
        for (int jj = 0; jj < 4; ++jj)
            hr[jj] = *(const float4*)&hbuf[4 * lr + 64 * jj];
#pragma unroll
        for (int j = 4; j < 8; ++j) {
            const int jj = j - 4;
            float tw;
            tw = fw[4*j+0] + ff[4*j+0]; pre = fmaf(hr[jj].x, tw, pre); nsq = fmaf(tw, tw, nsq);
            tw = fw[4*j+1] + ff[4*j+1]; pre = fmaf(hr[jj].y, tw, pre); nsq = fmaf(tw, tw, nsq);
            tw = fw[4*j+2] + ff[4*j+2]; pre = fmaf(hr[jj].z, tw, pre); nsq = fmaf(tw, tw, nsq);
            tw = fw[4*j+3] + ff[4*j+3]; pre = fmaf(hr[jj].w, tw, pre); nsq = fmaf(tw, tw, nsq);
        }
#pragma unroll
        for (int m = 1; m < 16; m <<= 1) {
            pre += __shfl_xor(pre, m, 16);
            nsq += __shfl_xor(nsq, m, 16);
        }
        const float inv = __fdividef(1.0f, sqrtf(nsq) + 1e-16f);
        // tanh(z) = 1 - 2/(exp(2z)+1); saturates cleanly to +-1.
        const float z   = fmaf(pre, inv, brow);
        const float e2  = __expf(2.0f * z);
        const float hn  = 1.0f - __fdividef(2.0f, e2 + 1.0f);

        if (lr == 0) {
            const unsigned long long pk =
                ((unsigned long long)(unsigned)(t + 1) << 32) |
                (unsigned long long)__float_as_uint(hn);
            __hip_atomic_store(
                hb + (size_t)(t & 1) * Bq * Hq + (size_t)b * Hq + row, pk,
                __ATOMIC_RELAXED, __HIP_MEMORY_SCOPE_AGENT);
        }

        // ---- shadow: f update (x re-read; h from hr regs) ----
        if (t < PRE_S) {
            const float* xpart = xall + t * Iq;
#pragma unroll
            for (int j = 0; j < 4; ++j) {
                const float4 tv = *(const float4*)&xpart[4 * lr + 64 * j];
                ff[4*j+0] = fmaf(fl[4*j+0], ff[4*j+0] * inv, fg[4*j+0] * (hn * tv.x));
                ff[4*j+1] = fmaf(fl[4*j+1], ff[4*j+1] * inv, fg[4*j+1] * (hn * tv.y));
                ff[4*j+2] = fmaf(fl[4*j+2], ff[4*j+2] * inv, fg[4*j+2] * (hn * tv.z));
                ff[4*j+3] = fmaf(fl[4*j+3], ff[4*j+3] * inv, fg[4*j+3] * (hn * tv.w));
            }
        } else {
            const float* xpart = xb + (size_t)t * Iq;
#pragma unroll
            for (int j = 0; j < 4; ++j) {
                const float4 tv = *(const float4*)&xpart[4 * lr + 64 * j];
                ff[4*j+0] = fmaf(fl[4*j+0], ff[4*j+0] * inv, fg[4*j+0] * (hn * tv.x));
                ff[4*j+1] = fmaf(fl[4*j+1], ff[4*j+1] * inv, fg[4*j+1] * (hn * tv.y));
                ff[4*j+2] = fmaf(fl[4*j+2], ff[4*j+2] * inv, fg[4*j+2] * (hn * tv.z));
                ff[4*j+3] = fmaf(fl[4*j+3], ff[4*j+3] * inv, fg[4*j+3] * (hn * tv.w));
            }
        }
#pragma unroll
        for (int j = 4; j < 8; ++j) {
            const int jj = j - 4;
            ff[4*j+0] = fmaf(fl[4*j+0], ff[4*j+0] * inv, fg[4*j+0] * (hn * hr[jj].x));
            ff[4*j+1] = fmaf(fl[4*j+1], ff[4*j+1] * inv, fg[4*j+1] * (hn * hr[jj].y));
            ff[4*j+2] = fmaf(fl[4*j+2], ff[4*j+2] * inv, fg[4*j+2] * (hn * hr[jj].z));
            ff[4*j+3] = fmaf(fl[4*j+3], ff[4*j+3] * inv, fg[4*j+3] * (hn * hr[jj].w));
        }
    }

    // ---- f_fin: 16 lanes x float4 per row chunk ----
    float* fo = out + Bq * Oq + Bq * Hq + (size_t)b * Hq * Fq + rowoff;
#pragma unroll
    for (int j = 0; j < 8; ++j) {
        const int c = 4 * lr + 64 * j;
        *(float4*)(fo + c) = *(const float4*)&ff[4*j];
    }

    // ---- epilogue (chunk-0 wg per batch): h_fin + tag_space ----
    if (chunk == 0) {
        __syncthreads();   // all waves past their last hbuf read before reuse
        if (tid < Hq) {    // 256 threads cover all Hq slots
            unsigned long long* slot =
                hb + (size_t)1 * Bq * Hq + (size_t)b * Hq + tid;  // t=63 -> parity 1
            unsigned long long v;
            do {
                v = __hip_atomic_load(slot, __ATOMIC_RELAXED,
                                      __HIP_MEMORY_SCOPE_AGENT);
            } while ((unsigned)(v >> 32) != (unsigned)Sq);
            const float hv = __uint_as_float((unsigned)(v & 0xffffffffu));
            hbuf[tid] = hv;
            out[Bq * Oq + (size_t)b * Hq + tid] = hv;     // h_fin
        }
        __syncthreads();
        // 256 threads = 128 outputs x 2 lanes; lane l sums cols 8k+4l..+3.
        const int o = tid >> 1;
        const int l = tid & 1;
        const float* wr = ow + (size_t)o * Hq;
        float acc = 0.f;
#pragma unroll
        for (int k = 0; k < 32; ++k) {
            const int cc = 8 * k + 4 * l;
            const float4 w4 = *(const float4*)(wr + cc);
            const float4 h4 = *(const float4*)&hbuf[cc];
            acc += w4.x * h4.x + w4.y * h4.y + w4.z * h4.z + w4.w * h4.w;
        }
        acc += __shfl_xor(acc, 1, 2);
        if (l == 0) out[(size_t)b * Oq + o] = acc + ob[o];
    }
}

extern "C" void kernel_launch(void* const* d_in, const int* in_sizes, int n_in,
                              void* d_out, int out_size, void* d_ws, size_t ws_size,
                              hipStream_t stream)
{
    const float* x    = (const float*)d_in[0];
    const float* w    = (const float*)d_in[1];
    const float* wl   = (const float*)d_in[2];
    const float* wgm  = (const float*)d_in[3];
    const float* bias = (const float*)d_in[4];
    const float* ow   = (const float*)d_in[5];
    const float* ob   = (const float*)d_in[6];
    float* out = (float*)d_out;

    // Zero the (tag,val) h-exchange slots: 2 * B * H * 8 bytes = 128 KB.
    hipMemsetAsync(d_ws, 0, 2 * Bq * Hq * sizeof(unsigned long long), stream);

    stpn_main<<<Bq * WPB, NT, 0, stream>>>(x, w, wl, wgm, bias, ow, ob, out,
                                           (unsigned long long*)d_ws);
}

// Round 11
// 151.807 us; speedup vs baseline: 1.2390x; 1.2390x over previous
//
#include <hip/hip_runtime.h>

// Problem dims (fixed by reference)
#define Bq 32
#define Sq 64
#define Iq 256
#define Hq 256
#define Oq 128
#define Fq 512          // Iq + Hq
#define WPB 8           // workgroups per batch
#define NT 512          // threads per workgroup
#define PRE_S 62        // x steps preloaded in LDS: 62KB + 1KB hbuf + flag <= 64KB

// R15: packed-FP32 issue-count cut on the R7 champion (98.7us).
// Ledger: transport structures (R2/R6), LLC-dodges (R12/R13), co-residency
// (R14) all closed -- every variant >=99us. Remaining lever: VALU issue
// count (VALUBusy~50% = ~1850cy/step/SIMD). Step time = max over 64 waves
// of (detect+compute+publish); cutting each wave's compute service time
// shrinks the max even when the mean path is latency-dominated.
// Change: elementwise-independent blocks packed into v_pk_*_f32 (CDNA
// packed fp32; compiler never auto-emits):
//   (a) tw = fw + ff        : 48 scalar adds -> 24 v_pk_add_f32
//   (b) f-update shadow     : 128 scalar ops -> 64 v_pk_{mul,fma}_f32
// pre/nsq accumulation chains stay scalar in the EXACT original sequence
// -> bit-identical numerics (absmax tripwire: exactly 0.0009765625).
// State arrays are f32x2 pairs so pk operands are aligned VGPR pairs
// (asm "v" also forces state out of AGPR bounce). Transport/tanh/epilogue
// are exact R7.
typedef float f32x2 __attribute__((ext_vector_type(2)));
typedef float f32x4 __attribute__((ext_vector_type(4)));

__global__ __launch_bounds__(NT, 1) void stpn_main(
    const float* __restrict__ x,     // (B,S,I)
    const float* __restrict__ w,     // (H,F)
    const float* __restrict__ wl,    // (H,F)
    const float* __restrict__ wgm,   // (H,F)
    const float* __restrict__ bias,  // (H)
    const float* __restrict__ ow,    // (O,H)
    const float* __restrict__ ob,    // (O)
    float* __restrict__ out,         // [tag(B*O) | h_fin(B*H) | f_fin(B*H*F)]
    unsigned long long* __restrict__ hb) // [2][B][H] (tag<<32|bits) slots
{
    const int blk   = blockIdx.x;
    const int b     = blk & 31;
    const int chunk = blk >> 5;       // 0..7
    const int h0    = chunk * 32;
    const int tid   = threadIdx.x;
    const int lr    = tid & 15;       // lane within row
    const int r     = tid >> 4;       // row 0..31
    const int row   = h0 + r;
    const int ln    = tid & 63;       // lane within wave
    const int wv    = tid >> 6;       // wave id within wg

    __shared__ float xall[PRE_S * Iq];   // 62 KB
    __shared__ float hbuf[Hq];           // 1 KB: h_{t-1} broadcast buffer
    __shared__ unsigned hflag;           // step tag of hbuf contents

    // Static params + fast-weight state as aligned register PAIRS.
    f32x2 fw2[16], fl2[16], fg2[16], ff2[16];
    const size_t rowoff = (size_t)row * Fq;
#pragma unroll
    for (int p = 0; p < 16; ++p) {
        const int c = 4 * lr + 64 * (p >> 1) + 2 * (p & 1);
        fw2[p] = *(const f32x2*)(w   + rowoff + c);
        fl2[p] = *(const f32x2*)(wl  + rowoff + c);
        fg2[p] = *(const f32x2*)(wgm + rowoff + c);
        ff2[p].x = 0.f; ff2[p].y = 0.f;
    }

    // Prologue x preload: 62*256/4 = 3968 float4 = 512*7 + 384.
    {
        const float4* xs = (const float4*)(x + (size_t)b * Sq * Iq);
        float4* xd = (float4*)xall;
#pragma unroll
        for (int k = 0; k < 7; ++k)
            xd[tid + NT * k] = xs[tid + NT * k];
        if (tid < 384) xd[tid + 3584] = xs[tid + 3584];
    }
    if (tid < Hq) hbuf[tid] = 0.f;    // t=0 reads h = 0
    if (tid == 0) hflag = 0u;
    const float brow = bias[row];
    const float* xb = x + (size_t)b * Sq * Iq;
    __syncthreads();                  // covers preload + hbuf/hflag init

    for (int t = 0; t < Sq; ++t) {
        // ---- x-part of fused pre+nsq (js 0..3): no transport dependency ----
        float pre = 0.f, nsq = 0.f;
        if (t < PRE_S) {
            const float* xpart = xall + t * Iq;
#pragma unroll
            for (int j = 0; j < 4; ++j) {
                const f32x4 tv = *(const f32x4*)&xpart[4 * lr + 64 * j];
                f32x2 tw01, tw23;
                asm("v_pk_add_f32 %0, %1, %2" : "=v"(tw01) : "v"(fw2[2*j]),   "v"(ff2[2*j]));
                asm("v_pk_add_f32 %0, %1, %2" : "=v"(tw23) : "v"(fw2[2*j+1]), "v"(ff2[2*j+1]));
                pre = fmaf(tv.x, tw01.x, pre); nsq = fmaf(tw01.x, tw01.x, nsq);
                pre = fmaf(tv.y, tw01.y, pre); nsq = fmaf(tw01.y, tw01.y, nsq);
                pre = fmaf(tv.z, tw23.x, pre); nsq = fmaf(tw23.x, tw23.x, nsq);
                pre = fmaf(tv.w, tw23.y, pre); nsq = fmaf(tw23.y, tw23.y, nsq);
            }
        } else {
            const float* xpart = xb + (size_t)t * Iq;
#pragma unroll
            for (int j = 0; j < 4; ++j) {
                const f32x4 tv = *(const f32x4*)&xpart[4 * lr + 64 * j];
                f32x2 tw01, tw23;
                asm("v_pk_add_f32 %0, %1, %2" : "=v"(tw01) : "v"(fw2[2*j]),   "v"(ff2[2*j]));
                asm("v_pk_add_f32 %0, %1, %2" : "=v"(tw23) : "v"(fw2[2*j+1]), "v"(ff2[2*j+1]));
                pre = fmaf(tv.x, tw01.x, pre); nsq = fmaf(tw01.x, tw01.x, nsq);
                pre = fmaf(tv.y, tw01.y, pre); nsq = fmaf(tw01.y, tw01.y, nsq);
                pre = fmaf(tv.z, tw23.x, pre); nsq = fmaf(tw23.x, tw23.x, nsq);
                pre = fmaf(tv.w, tw23.y, pre); nsq = fmaf(tw23.y, tw23.y, nsq);
            }
        }

        // ---- transport: wave0 fetches h_{t-1}, siblings wait on LDS flag ----
        if (t > 0) {
            const unsigned tt = (unsigned)t;
            if (wv == 0) {
                unsigned long long* s0 =
                    hb + (size_t)((t - 1) & 1) * Bq * Hq + (size_t)b * Hq + ln;
                unsigned long long v0, v1, v2, v3;
                do {
                    v0 = __hip_atomic_load(s0,       __ATOMIC_RELAXED, __HIP_MEMORY_SCOPE_AGENT);
                    v1 = __hip_atomic_load(s0 + 64,  __ATOMIC_RELAXED, __HIP_MEMORY_SCOPE_AGENT);
                    v2 = __hip_atomic_load(s0 + 128, __ATOMIC_RELAXED, __HIP_MEMORY_SCOPE_AGENT);
                    v3 = __hip_atomic_load(s0 + 192, __ATOMIC_RELAXED, __HIP_MEMORY_SCOPE_AGENT);
                } while (!((unsigned)(v0 >> 32) == tt && (unsigned)(v1 >> 32) == tt &&
                           (unsigned)(v2 >> 32) == tt && (unsigned)(v3 >> 32) == tt));
                hbuf[ln      ] = __uint_as_float((unsigned)(v0 & 0xffffffffu));
                hbuf[ln + 64 ] = __uint_as_float((unsigned)(v1 & 0xffffffffu));
                hbuf[ln + 128] = __uint_as_float((unsigned)(v2 & 0xffffffffu));
                hbuf[ln + 192] = __uint_as_float((unsigned)(v3 & 0xffffffffu));
                if (ln == 0)
                    __hip_atomic_store(&hflag, tt, __ATOMIC_RELEASE,
                                       __HIP_MEMORY_SCOPE_WORKGROUP);
            } else {
                while (__hip_atomic_load(&hflag, __ATOMIC_ACQUIRE,
                                         __HIP_MEMORY_SCOPE_WORKGROUP) != tt) {}
            }
        }

        // ---- h-part (js 4..7); keep operands in regs for the shadow ----
        f32x4 h4[4];
#pragma unroll
        for (int jj = 0; jj < 4; ++jj)
            h4[jj] = *(const f32x4*)&hbuf[4 * lr + 64 * jj];
#pragma unroll
        for (int j = 4; j < 8; ++j) {
            const int jj = j - 4;
            f32x2 tw01, tw23;
            asm("v_pk_add_f32 %0, %1, %2" : "=v"(tw01) : "v"(fw2[2*j]),   "v"(ff2[2*j]));
            asm("v_pk_add_f32 %0, %1, %2" : "=v"(tw23) : "v"(fw2[2*j+1]), "v"(ff2[2*j+1]));
            pre = fmaf(h4[jj].x, tw01.x, pre); nsq = fmaf(tw01.x, tw01.x, nsq);
            pre = fmaf(h4[jj].y, tw01.y, pre); nsq = fmaf(tw01.y, tw01.y, nsq);
            pre = fmaf(h4[jj].z, tw23.x, pre); nsq = fmaf(tw23.x, tw23.x, nsq);
            pre = fmaf(h4[jj].w, tw23.y, pre); nsq = fmaf(tw23.y, tw23.y, nsq);
        }
#pragma unroll
        for (int m = 1; m < 16; m <<= 1) {
            pre += __shfl_xor(pre, m, 16);
            nsq += __shfl_xor(nsq, m, 16);
        }
        const float inv = __fdividef(1.0f, sqrtf(nsq) + 1e-16f);
        // tanh(z) = 1 - 2/(exp(2z)+1); saturates cleanly to +-1.
        const float z   = fmaf(pre, inv, brow);
        const float e2  = __expf(2.0f * z);
        const float hn  = 1.0f - __fdividef(2.0f, e2 + 1.0f);

        if (lr == 0) {
            const unsigned long long pk =
                ((unsigned long long)(unsigned)(t + 1) << 32) |
                (unsigned long long)__float_as_uint(hn);
            __hip_atomic_store(
                hb + (size_t)(t & 1) * Bq * Hq + (size_t)b * Hq + row, pk,
                __ATOMIC_RELAXED, __HIP_MEMORY_SCOPE_AGENT);
        }

        // ---- shadow: f update, packed. Per element (bit-exact vs scalar):
        //   t1 = ff*inv; t2 = hn*tv; t3 = fg*t2; ff = fma(fl, t1, t3)
        f32x2 hn2;  hn2.x  = hn;  hn2.y  = hn;
        f32x2 inv2; inv2.x = inv; inv2.y = inv;
#define PK_FF(IDX, TVP) do {                                               \
            f32x2 t1, t2, t3;                                              \
            asm("v_pk_mul_f32 %0, %1, %2" : "=v"(t1) : "v"(ff2[IDX]), "v"(inv2)); \
            asm("v_pk_mul_f32 %0, %1, %2" : "=v"(t2) : "v"(hn2), "v"(TVP));       \
            asm("v_pk_mul_f32 %0, %1, %2" : "=v"(t3) : "v"(fg2[IDX]), "v"(t2));   \
            asm("v_pk_fma_f32 %0, %1, %2, %3"                              \
                : "=v"(ff2[IDX]) : "v"(fl2[IDX]), "v"(t1), "v"(t3));       \
        } while (0)

        if (t < PRE_S) {
            const float* xpart = xall + t * Iq;
#pragma unroll
            for (int j = 0; j < 4; ++j) {
                const f32x4 tv = *(const f32x4*)&xpart[4 * lr + 64 * j];
                const f32x2 tva = __builtin_shufflevector(tv, tv, 0, 1);
                const f32x2 tvb = __builtin_shufflevector(tv, tv, 2, 3);
                PK_FF(2*j,   tva);
                PK_FF(2*j+1, tvb);
            }
        } else {
            const float* xpart = xb + (size_t)t * Iq;
#pragma unroll
            for (int j = 0; j < 4; ++j) {
                const f32x4 tv = *(const f32x4*)&xpart[4 * lr + 64 * j];
                const f32x2 tva = __builtin_shufflevector(tv, tv, 0, 1);
                const f32x2 tvb = __builtin_shufflevector(tv, tv, 2, 3);
                PK_FF(2*j,   tva);
                PK_FF(2*j+1, tvb);
            }
        }
#pragma unroll
        for (int j = 4; j < 8; ++j) {
            const int jj = j - 4;
            const f32x2 hva = __builtin_shufflevector(h4[jj], h4[jj], 0, 1);
            const f32x2 hvb = __builtin_shufflevector(h4[jj], h4[jj], 2, 3);
            PK_FF(2*j,   hva);
            PK_FF(2*j+1, hvb);
        }
#undef PK_FF
    }

    // ---- f_fin: 16 lanes x f32x2 pairs per row chunk ----
    float* fo = out + Bq * Oq + Bq * Hq + (size_t)b * Hq * Fq + rowoff;
#pragma unroll
    for (int p = 0; p < 16; ++p) {
        const int c = 4 * lr + 64 * (p >> 1) + 2 * (p & 1);
        *(f32x2*)(fo + c) = ff2[p];
    }

    // ---- epilogue (chunk-0 wg per batch): h_fin + tag_space ----
    if (chunk == 0) {
        __syncthreads();   // all waves past their last hbuf read before reuse
        if (tid < Hq) {
            unsigned long long* slot =
                hb + (size_t)1 * Bq * Hq + (size_t)b * Hq + tid;  // t=63 -> parity 1
            unsigned long long v;
            do {
                v = __hip_atomic_load(slot, __ATOMIC_RELAXED,
                                      __HIP_MEMORY_SCOPE_AGENT);
            } while ((unsigned)(v >> 32) != (unsigned)Sq);
            const float hv = __uint_as_float((unsigned)(v & 0xffffffffu));
            hbuf[tid] = hv;
            out[Bq * Oq + (size_t)b * Hq + tid] = hv;     // h_fin
        }
        __syncthreads();
        // 512 threads = 128 outputs x 4 lanes; lane l sums cols 16k+4l..+3.
        const int o = tid >> 2;
        const int l = tid & 3;
        const float* wr = ow + (size_t)o * Hq;
        float acc = 0.f;
#pragma unroll
        for (int k = 0; k < 16; ++k) {
            const int cc = 16 * k + 4 * l;
            const float4 w4 = *(const float4*)(wr + cc);
            const float4 h4e = *(const float4*)&hbuf[cc];
            acc += w4.x * h4e.x + w4.y * h4e.y + w4.z * h4e.z + w4.w * h4e.w;
        }
        acc += __shfl_xor(acc, 1, 4);
        acc += __shfl_xor(acc, 2, 4);
        if (l == 0) out[(size_t)b * Oq + o] = acc + ob[o];
    }
}

extern "C" void kernel_launch(void* const* d_in, const int* in_sizes, int n_in,
                              void* d_out, int out_size, void* d_ws, size_t ws_size,
                              hipStream_t stream)
{
    const float* x    = (const float*)d_in[0];
    const float* w    = (const float*)d_in[1];
    const float* wl   = (const float*)d_in[2];
    const float* wgm  = (const float*)d_in[3];
    const float* bias = (const float*)d_in[4];
    const float* ow   = (const float*)d_in[5];
    const float* ob   = (const float*)d_in[6];
    float* out = (float*)d_out;

    // Zero the (tag,val) h-exchange slots: 2 * B * H * 8 bytes = 128 KB.
    hipMemsetAsync(d_ws, 0, 2 * Bq * Hq * sizeof(unsigned long long), stream);

    stpn_main<<<Bq * WPB, NT, 0, stream>>>(x, w, wl, wgm, bias, ow, ob, out,
                                           (unsigned long long*)d_ws);
}